// Round 17
// baseline (313.363 us; speedup 1.0000x reference)
//
#include <hip/hip_runtime.h>
#include <hip/hip_bf16.h>
#include <math.h>

// Problem constants
#define B_ 2
#define L_ 1000
#define D_ 288
#define H_ 8
#define DIM_ 36
#define DFF_ 576
#define KS_ 250
#define NQ_ 250
#define BH_ (B_ * H_)
#define EPS_ 1e-5f
#define PSTRIDE_ 40             // partial row: 36 acc + 1 sum, padded to 40

__device__ __forceinline__ float gelu_exact(float x) {
    return 0.5f * x * (1.0f + erff(x * 0.70710678118654752f));
}

__device__ __forceinline__ float dot4(float4 a, float4 b) {
    return a.x * b.x + a.y * b.y + a.z * b.z + a.w * b.w;
}

// ---------------------------------------------------------------------------
// K0a: merged QKV weight transpose (3 x 288x288 in one launch). grid 243.
// ---------------------------------------------------------------------------
__global__ __launch_bounds__(256) void qkv_transpose_kernel(
    const float* __restrict__ Wq, const float* __restrict__ Wk,
    const float* __restrict__ Wv,
    float* __restrict__ WqT, float* __restrict__ WkT, float* __restrict__ WvT)
{
    __shared__ float tile[32][33];
    const int m = blockIdx.x / 81;
    const int t = blockIdx.x % 81;
    const float* src = (m == 0) ? Wq : (m == 1) ? Wk : Wv;
    float* dst = (m == 0) ? WqT : (m == 1) ? WkT : WvT;
    const int ty0 = (t / 9) * 32, tx0 = (t % 9) * 32;
    const int tx = threadIdx.x & 31, ty = threadIdx.x >> 5;
#pragma unroll
    for (int i = 0; i < 4; i++)
        tile[ty + 8 * i][tx] = src[(size_t)(ty0 + ty + 8 * i) * D_ + tx0 + tx];
    __syncthreads();
#pragma unroll
    for (int i = 0; i < 4; i++)
        dst[(size_t)(tx0 + ty + 8 * i) * D_ + ty0 + tx] = tile[tx][ty + 8 * i];
}

// ---------------------------------------------------------------------------
// K0c: merged FFN weight transpose: W1[576][288]->W1T, W2[288][576]->W2T.
// grid 324 (162 tiles each).
// ---------------------------------------------------------------------------
__global__ __launch_bounds__(256) void ffn_transpose_kernel(
    const float* __restrict__ W1, const float* __restrict__ W2,
    float* __restrict__ W1T, float* __restrict__ W2T)
{
    __shared__ float tile[32][33];
    int t = blockIdx.x;
    const float* src; float* dst; int Rr, Cc, ntx;
    if (t < 162) { src = W1; dst = W1T; Rr = DFF_; Cc = D_; ntx = 9; }
    else { t -= 162; src = W2; dst = W2T; Rr = D_; Cc = DFF_; ntx = 18; }
    const int ty0 = (t / ntx) * 32, tx0 = (t % ntx) * 32;
    const int tx = threadIdx.x & 31, ty = threadIdx.x >> 5;
#pragma unroll
    for (int i = 0; i < 4; i++)
        tile[ty + 8 * i][tx] = src[(size_t)(ty0 + ty + 8 * i) * Cc + tx0 + tx];
    __syncthreads();
#pragma unroll
    for (int i = 0; i < 4; i++)
        dst[(size_t)(tx0 + ty + 8 * i) * Rr + ty0 + tx] = tile[tx][ty + 8 * i];
}

// ---------------------------------------------------------------------------
// K0b: batched K transpose: K[bh][l][d] -> KT[bh][d][l]. grid 1024.
// ---------------------------------------------------------------------------
__global__ __launch_bounds__(256) void ktranspose_kernel(
    const float* __restrict__ K, float* __restrict__ KT)
{
    __shared__ float tile[32][33];
    const int t = blockIdx.x;
    const int bh = t >> 6;
    const int rem = t & 63;
    const int lt = rem >> 1, dt = rem & 1;
    const int l0 = lt * 32, d0 = dt * 32;
    const int tx = threadIdx.x & 31, ty = threadIdx.x >> 5;
    const float* Kb = K + (size_t)bh * L_ * DIM_;
    float* KTb = KT + (size_t)bh * DIM_ * L_;
#pragma unroll
    for (int i = 0; i < 4; i++) {
        int l = l0 + ty + 8 * i, d = d0 + tx;
        tile[ty + 8 * i][tx] = (l < L_ && d < DIM_) ? Kb[(size_t)l * DIM_ + d] : 0.f;
    }
    __syncthreads();
#pragma unroll
    for (int i = 0; i < 4; i++) {
        int d = d0 + ty + 8 * i, l = l0 + tx;
        if (d < DIM_ && l < L_) KTb[(size_t)d * L_ + l] = tile[tx][ty + 8 * i];
    }
}

// ---------------------------------------------------------------------------
// K1: QKV: register-tiled 4 cols x 4 rows. grid 500, block 256.
// ---------------------------------------------------------------------------
__global__ __launch_bounds__(256) void qkvT2_kernel(
    const float* __restrict__ x,
    const float* __restrict__ WqT, const float* __restrict__ WkT,
    const float* __restrict__ WvT,
    const float* __restrict__ bq, const float* __restrict__ bk,
    const float* __restrict__ bv,
    float* __restrict__ Q, float* __restrict__ K, float* __restrict__ V)
{
    __shared__ float xsT[D_][4];        // [k][r]
    const int base = blockIdx.x * 4;
    const int tid = threadIdx.x;

    for (int idx = tid; idx < 4 * D_; idx += 256) {
        int r = idx / D_, k = idx % D_;
        xsT[k][r] = x[(size_t)(base + r) * D_ + k];
    }
    __syncthreads();

    if (tid < 216) {
        const int gcol = 4 * tid;              // 0..863
        const int m = gcol / D_;
        const int c = gcol - m * D_;
        const float* WT = (m == 0) ? WqT : (m == 1) ? WkT : WvT;
        const float* bias = (m == 0) ? bq : (m == 1) ? bk : bv;
        float* outp = (m == 0) ? Q : (m == 1) ? K : V;

        float a[4][4];
#pragma unroll
        for (int j = 0; j < 4; j++) {
            float bv2 = bias[c + j];
#pragma unroll
            for (int r = 0; r < 4; r++) a[j][r] = bv2;
        }

        for (int k = 0; k < D_; k++) {
            float4 w = *(const float4*)(WT + (size_t)k * D_ + c);
            float4 xv = *(const float4*)&xsT[k][0];
            a[0][0] += w.x * xv.x; a[0][1] += w.x * xv.y; a[0][2] += w.x * xv.z; a[0][3] += w.x * xv.w;
            a[1][0] += w.y * xv.x; a[1][1] += w.y * xv.y; a[1][2] += w.y * xv.z; a[1][3] += w.y * xv.w;
            a[2][0] += w.z * xv.x; a[2][1] += w.z * xv.y; a[2][2] += w.z * xv.z; a[2][3] += w.z * xv.w;
            a[3][0] += w.w * xv.x; a[3][1] += w.w * xv.y; a[3][2] += w.w * xv.z; a[3][3] += w.w * xv.w;
        }

#pragma unroll
        for (int j = 0; j < 4; j++) {
            int col = c + j;
            int h = col / DIM_, dd = col % DIM_;
#pragma unroll
            for (int r = 0; r < 4; r++) {
                int row = base + r;
                int b = row / L_, l = row % L_;
                outp[((size_t)(b * H_ + h) * L_ + l) * DIM_ + dd] = a[j][r];
            }
        }
    }
}

// ---------------------------------------------------------------------------
// K1-fallback: qkv with row-major weights.
// ---------------------------------------------------------------------------
__global__ __launch_bounds__(320) void qkv_kernel(
    const float* __restrict__ x,
    const float* __restrict__ Wq, const float* __restrict__ bq,
    const float* __restrict__ Wk, const float* __restrict__ bk,
    const float* __restrict__ Wv, const float* __restrict__ bv,
    float* __restrict__ Q, float* __restrict__ K, float* __restrict__ V)
{
    constexpr int R = 8;
    __shared__ float xs[R][D_];
    const int base = blockIdx.x * R;
    const int tid = threadIdx.x;

    const float4* xsrc = (const float4*)(x + (size_t)base * D_);
    float4* xdst = (float4*)&xs[0][0];
    for (int i = tid; i < R * D_ / 4; i += 320) xdst[i] = xsrc[i];
    __syncthreads();

    if (tid < D_) {
        const float4* wq4 = (const float4*)(Wq + (size_t)tid * D_);
        const float4* wk4 = (const float4*)(Wk + (size_t)tid * D_);
        const float4* wv4 = (const float4*)(Wv + (size_t)tid * D_);
        float aq[R], ak[R], av[R];
        float biasq = bq[tid], biask = bk[tid], biasv = bv[tid];
#pragma unroll
        for (int r = 0; r < R; r++) { aq[r] = biasq; ak[r] = biask; av[r] = biasv; }
        for (int d4 = 0; d4 < D_ / 4; d4++) {
            float4 wqv = wq4[d4], wkv = wk4[d4], wvv = wv4[d4];
#pragma unroll
            for (int r = 0; r < R; r++) {
                float4 hv = *(const float4*)&xs[r][d4 * 4];
                aq[r] += dot4(hv, wqv);
                ak[r] += dot4(hv, wkv);
                av[r] += dot4(hv, wvv);
            }
        }
        const int h = tid / DIM_, dd = tid % DIM_;
#pragma unroll
        for (int r = 0; r < R; r++) {
            int row = base + r;
            int b = row / L_, l = row % L_;
            size_t o = ((size_t)(b * H_ + h) * L_ + l) * DIM_ + dd;
            Q[o] = aq[r]; K[o] = ak[r]; V[o] = av[r];
        }
    }
}

// ---------------------------------------------------------------------------
// K2: Vmean[bh, d]. Block per bh.
// ---------------------------------------------------------------------------
__global__ __launch_bounds__(256) void vmean_kernel(
    const float* __restrict__ V, float* __restrict__ Vmean)
{
    const int bh = blockIdx.x;
    const int tid = threadIdx.x;
    __shared__ float red[7][DIM_];
    if (tid < 252) {
        int g = tid / DIM_, d = tid % DIM_;
        const float* base = V + (size_t)bh * L_ * DIM_;
        float s = 0.f;
        for (int l = g; l < L_; l += 7) s += base[l * DIM_ + d];
        red[g][d] = s;
    }
    __syncthreads();
    if (tid < DIM_) {
        float s = 0.f;
#pragma unroll
        for (int g = 0; g < 7; g++) s += red[g][tid];
        Vmean[bh * DIM_ + tid] = s * (1.0f / L_);
    }
}

// ---------------------------------------------------------------------------
// K3: FUSED score+measure: KT coalesced scalar loads (lane = key),
// acc[8] register shape. grid 2000, block 256.
// ---------------------------------------------------------------------------
__global__ __launch_bounds__(256) void score_measure3_kernel(
    const float* __restrict__ Q, const float* __restrict__ KT,
    const int* __restrict__ index_key, float* __restrict__ measure)
{
    constexpr int R = 8;
    __shared__ float qs[R][DIM_];
    __shared__ float st[R][1004];
    const int bh = blockIdx.x / 125;
    const int qt = blockIdx.x % 125;
    const int tid = threadIdx.x;

    if (tid < R * DIM_ / 4)
        ((float4*)&qs[0][0])[tid] =
            ((const float4*)(Q + ((size_t)bh * L_ + qt * R) * DIM_))[tid];
    __syncthreads();

    const float* KTb = KT + (size_t)bh * DIM_ * L_;
#pragma unroll
    for (int i = 0; i < 4; i++) {
        const int k = i * 256 + tid;
        if (k < L_) {
            float acc[R];
#pragma unroll
            for (int r = 0; r < R; r++) acc[r] = 0.f;
#pragma unroll
            for (int d4 = 0; d4 < DIM_ / 4; d4++) {
                float4 kv;
                kv.x = KTb[(size_t)(d4 * 4 + 0) * L_ + k];
                kv.y = KTb[(size_t)(d4 * 4 + 1) * L_ + k];
                kv.z = KTb[(size_t)(d4 * 4 + 2) * L_ + k];
                kv.w = KTb[(size_t)(d4 * 4 + 3) * L_ + k];
#pragma unroll
                for (int r = 0; r < R; r++)
                    acc[r] += dot4(*(const float4*)&qs[r][d4 * 4], kv);
            }
#pragma unroll
            for (int r = 0; r < R; r++) st[r][k] = acc[r];
        }
    }
    __syncthreads();

    // measure: lane-group of 32 per query
    const int r = tid >> 5;             // 0..7
    const int lane = tid & 31;
    const int l = qt * R + r;
    const int* ik = index_key + l * KS_;
    float mx = -1e30f, sm = 0.f;
    for (int s = lane; s < KS_; s += 32) {
        float v = st[r][ik[s]];
        mx = fmaxf(mx, v);
        sm += v;
    }
#pragma unroll
    for (int off = 16; off; off >>= 1) {
        mx = fmaxf(mx, __shfl_xor(mx, off));
        sm += __shfl_xor(sm, off);
    }
    if (lane == 0) measure[bh * L_ + l] = mx - sm * (1.0f / (float)L_);
}

// ---------------------------------------------------------------------------
// K3-fallback: gather-based measure.
// ---------------------------------------------------------------------------
__global__ __launch_bounds__(256) void measure_kernel(
    const float* __restrict__ Q, const float* __restrict__ K,
    const int* __restrict__ index_key, float* __restrict__ measure)
{
    const int w = threadIdx.x >> 6;
    const int lane = threadIdx.x & 63;
    const int wid = blockIdx.x * 4 + w;
    const int bh = wid / L_;
    const int l = wid % L_;

    const float4* qp = (const float4*)(Q + ((size_t)bh * L_ + l) * DIM_);
    float4 q[9];
#pragma unroll
    for (int i = 0; i < 9; i++) q[i] = qp[i];

    const int* ik = index_key + l * KS_;
    const float* Kb = K + (size_t)bh * L_ * DIM_;

    float mx = -1e30f, sm = 0.f;
#pragma unroll
    for (int s = lane; s < KS_; s += 64) {
        int kidx = ik[s];
        const float4* k4 = (const float4*)(Kb + (size_t)kidx * DIM_);
        float acc = 0.f;
#pragma unroll
        for (int i = 0; i < 9; i++) acc += dot4(q[i], k4[i]);
        mx = fmaxf(mx, acc);
        sm += acc;
    }
#pragma unroll
    for (int off = 32; off; off >>= 1) {
        mx = fmaxf(mx, __shfl_xor(mx, off));
        sm += __shfl_xor(sm, off);
    }
    if (lane == 0) measure[wid] = mx - sm * (1.0f / (float)L_);
}

// ---------------------------------------------------------------------------
// K4: top-NQ v2: rank IS the slot (deterministic, matches lax.top_k order).
// No atomics, no memset: writes full slot_map + qlist. grid 16, block 1024.
// ---------------------------------------------------------------------------
__global__ __launch_bounds__(1024) void topk2_kernel(
    const float* __restrict__ measure, int* __restrict__ qlist,
    int* __restrict__ slot_map)
{
    const int bh = blockIdx.x;
    __shared__ float m[L_];
    const int tid = threadIdx.x;
    for (int i = tid; i < L_; i += 1024) m[i] = measure[bh * L_ + i];
    __syncthreads();
    if (tid < L_) {
        float mi = m[tid];
        int rank = 0;
        for (int j = 0; j < L_; j++) {
            float mj = m[j];
            rank += (mj > mi) || (mj == mi && j < tid);
        }
        if (rank < NQ_) qlist[bh * NQ_ + rank] = tid;
        slot_map[bh * L_ + tid] = (rank < NQ_) ? rank : -1;
    }
}

// ---------------------------------------------------------------------------
// K6: attention partials via K-dot recompute, wave-uniform K/V loads.
// grid BH_*nchunk, block 256 (250 active).
// ---------------------------------------------------------------------------
__global__ __launch_bounds__(256) void attn_part_kernel(
    const float* __restrict__ Q, const float* __restrict__ K,
    const float* __restrict__ V, const int* __restrict__ qlist,
    float* __restrict__ part, int nchunk, int chunk_len)
{
    const int bh = blockIdx.x / nchunk;
    const int chunk = blockIdx.x % nchunk;
    const int slot = threadIdx.x;
    if (slot >= NQ_) return;

    const int qidx = qlist[bh * NQ_ + slot];
    const float4* qp = (const float4*)(Q + ((size_t)bh * L_ + qidx) * DIM_);
    float4 q[9];
#pragma unroll
    for (int i = 0; i < 9; i++) q[i] = qp[i];

    const float* Kb = K + (size_t)bh * L_ * DIM_;
    const float* Vb = V + (size_t)bh * L_ * DIM_;
    const float scale = (float)(1.0 / 6.0);

    float4 acc[9];
#pragma unroll
    for (int i = 0; i < 9; i++) acc[i] = make_float4(0.f, 0.f, 0.f, 0.f);
    float sum = 0.f;

    const int k0 = chunk * chunk_len;
    for (int j = 0; j < chunk_len; j++) {
        const int key = k0 + j;                       // wave-uniform
        const float4* kp = (const float4*)(Kb + (size_t)key * DIM_);
        float s = 0.f;
#pragma unroll
        for (int i = 0; i < 9; i++) s += dot4(q[i], kp[i]);
        float e = __expf(s * scale);
        sum += e;
        const float4* vp = (const float4*)(Vb + (size_t)key * DIM_);
#pragma unroll
        for (int i = 0; i < 9; i++) {
            float4 vv = vp[i];
            acc[i].x += e * vv.x;
            acc[i].y += e * vv.y;
            acc[i].z += e * vv.z;
            acc[i].w += e * vv.w;
        }
    }

    float* p = part + ((size_t)(bh * NQ_ + slot) * nchunk + chunk) * PSTRIDE_;
#pragma unroll
    for (int i = 0; i < 9; i++) ((float4*)p)[i] = acc[i];
    p[DIM_] = sum;
}

// ---------------------------------------------------------------------------
// K7: combine_all: one thread per (b,l,d-full) element. Lazy rows take
// Vmean; selected rows reduce their chunk partials (same per-element cost
// as the old fill+combine pair, one dispatch). grid 2250, block 256.
// ---------------------------------------------------------------------------
__global__ __launch_bounds__(256) void combine_all_kernel(
    const float* __restrict__ part, const int* __restrict__ slot_map,
    const float* __restrict__ Vmean, float* __restrict__ attn_out, int nchunk)
{
    int idx = blockIdx.x * blockDim.x + threadIdx.x;
    if (idx >= B_ * L_ * D_) return;
    int dfull = idx % D_;
    int bl = idx / D_;
    int b = bl / L_, l = bl % L_;
    int h = dfull / DIM_, d = dfull % DIM_;
    int bh = b * H_ + h;
    int slot = slot_map[bh * L_ + l];
    float v;
    if (slot < 0) {
        v = Vmean[bh * DIM_ + d];
    } else {
        const float* p = part + (size_t)(bh * NQ_ + slot) * nchunk * PSTRIDE_;
        float a = 0.f, s = 0.f;
        for (int c = 0; c < nchunk; c++) {
            a += p[c * PSTRIDE_ + d];
            s += p[c * PSTRIDE_ + DIM_];
        }
        v = a / s;
    }
    attn_out[idx] = v;
}

// ---------------------------------------------------------------------------
// K8: LN1: h1 = LayerNorm(x + attn_out). One wave per row.
// ---------------------------------------------------------------------------
__global__ __launch_bounds__(64) void ln1_kernel(
    const float* __restrict__ x, const float* __restrict__ attn,
    const float* __restrict__ g, const float* __restrict__ bb,
    float* __restrict__ h1)
{
    const int row = blockIdx.x;
    const int lane = threadIdx.x;
    const float* xr = x + (size_t)row * D_;
    const float* ar = attn + (size_t)row * D_;

    float vals[5];
    float s = 0.f;
#pragma unroll
    for (int i = 0; i < 5; i++) {
        int j = lane + i * 64;
        float v = (j < D_) ? (xr[j] + ar[j]) : 0.f;
        vals[i] = v;
        s += v;
    }
#pragma unroll
    for (int off = 32; off; off >>= 1) s += __shfl_xor(s, off);
    float mu = s * (1.0f / D_);

    float vs = 0.f;
#pragma unroll
    for (int i = 0; i < 5; i++) {
        int j = lane + i * 64;
        if (j < D_) { float dd = vals[i] - mu; vs += dd * dd; }
    }
#pragma unroll
    for (int off = 32; off; off >>= 1) vs += __shfl_xor(vs, off);
    float rstd = rsqrtf(vs * (1.0f / D_) + EPS_);

#pragma unroll
    for (int i = 0; i < 5; i++) {
        int j = lane + i * 64;
        if (j < D_) h1[(size_t)row * D_ + j] = (vals[i] - mu) * rstd * g[j] + bb[j];
    }
}

// ---------------------------------------------------------------------------
// K9: FUSED FFN v2b (R16): conflict-free LDS layouts. grid 500, block 288.
// ---------------------------------------------------------------------------
__global__ __launch_bounds__(288) void ffn_fused2b_kernel(
    const float* __restrict__ h1,
    const float* __restrict__ W1T, const float* __restrict__ b1,
    const float* __restrict__ W2T, const float* __restrict__ b2,
    const float* __restrict__ g, const float* __restrict__ bb,
    float* __restrict__ out)
{
    __shared__ float hs[4][D_];
    __shared__ float fs[4][DFF_];
    __shared__ float red[3456];
    __shared__ float ys[4][D_];
    const int base = blockIdx.x * 4;
    const int tid = threadIdx.x;

    {
        const float4* src = (const float4*)(h1 + (size_t)base * D_);
        float4* dst = (float4*)&hs[0][0];
        for (int i = tid; i < 4 * D_ / 4; i += 288) dst[i] = src[i];
    }
    __syncthreads();

    // phase 1: f = gelu(h1 @ W1T + b1), 2-way k-split
    {
        const int kg = tid / 144;
        const int ct = tid - kg * 144;
        const int c = 4 * ct;
        float a[4][4];
        if (kg == 0) {
#pragma unroll
            for (int j = 0; j < 4; j++) {
                float bv = b1[c + j];
#pragma unroll
                for (int r = 0; r < 4; r++) a[j][r] = bv;
            }
        } else {
#pragma unroll
            for (int j = 0; j < 4; j++)
#pragma unroll
                for (int r = 0; r < 4; r++) a[j][r] = 0.f;
        }
        const int kbeg = kg * 144;
        for (int k = kbeg; k < kbeg + 144; k++) {
            float4 w = *(const float4*)(W1T + (size_t)k * DFF_ + c);
            float x0 = hs[0][k], x1 = hs[1][k], x2 = hs[2][k], x3 = hs[3][k];
            a[0][0] += w.x * x0; a[0][1] += w.x * x1; a[0][2] += w.x * x2; a[0][3] += w.x * x3;
            a[1][0] += w.y * x0; a[1][1] += w.y * x1; a[1][2] += w.y * x2; a[1][3] += w.y * x3;
            a[2][0] += w.z * x0; a[2][1] += w.z * x1; a[2][2] += w.z * x2; a[2][3] += w.z * x3;
            a[3][0] += w.w * x0; a[3][1] += w.w * x1; a[3][2] += w.w * x2; a[3][3] += w.w * x3;
        }
        if (kg == 1) {
#pragma unroll
            for (int j = 0; j < 4; j++)
                *(float4*)&red[(j * 144 + ct) * 4] =
                    make_float4(a[j][0], a[j][1], a[j][2], a[j][3]);
        }
        __syncthreads();
        if (kg == 0) {
            float y[4][4];
#pragma unroll
            for (int j = 0; j < 4; j++) {
                float4 o = *(const float4*)&red[(j * 144 + ct) * 4];
                y[j][0] = gelu_exact(a[j][0] + o.x);
                y[j][1] = gelu_exact(a[j][1] + o.y);
                y[j][2] = gelu_exact(a[j][2] + o.z);
                y[j][3] = gelu_exact(a[j][3] + o.w);
            }
#pragma unroll
            for (int r = 0; r < 4; r++)
                *(float4*)&fs[r][c] = make_float4(y[0][r], y[1][r], y[2][r], y[3][r]);
        }
    }
    __syncthreads();

    // phase 2: y = gelu(f @ W2T + b2) + h1, 4-way k-split
    {
        const int kg = tid / 72;
        const int ct = tid - kg * 72;
        const int c = 4 * ct;
        float a[4][4];
        if (kg == 0) {
#pragma unroll
            for (int j = 0; j < 4; j++) {
                float bv = b2[c + j];
#pragma unroll
                for (int r = 0; r < 4; r++) a[j][r] = bv;
            }
        } else {
#pragma unroll
            for (int j = 0; j < 4; j++)
#pragma unroll
                for (int r = 0; r < 4; r++) a[j][r] = 0.f;
        }
        const int kbeg = kg * 144;
        for (int k = kbeg; k < kbeg + 144; k++) {
            float4 w = *(const float4*)(W2T + (size_t)k * D_ + c);
            float f0 = fs[0][k], f1 = fs[1][k], f2 = fs[2][k], f3 = fs[3][k];
            a[0][0] += w.x * f0; a[0][1] += w.x * f1; a[0][2] += w.x * f2; a[0][3] += w.x * f3;
            a[1][0] += w.y * f0; a[1][1] += w.y * f1; a[1][2] += w.y * f2; a[1][3] += w.y * f3;
            a[2][0] += w.z * f0; a[2][1] += w.z * f1; a[2][2] += w.z * f2; a[2][3] += w.z * f3;
            a[3][0] += w.w * f0; a[3][1] += w.w * f1; a[3][2] += w.w * f2; a[3][3] += w.w * f3;
        }
        if (kg >= 1) {
#pragma unroll
            for (int j = 0; j < 4; j++)
                *(float4*)&red[(((kg - 1) * 4 + j) * 72 + ct) * 4] =
                    make_float4(a[j][0], a[j][1], a[j][2], a[j][3]);
        }
        __syncthreads();
        if (kg == 0) {
            float y[4][4];
#pragma unroll
            for (int j = 0; j < 4; j++) {
                float4 o0 = *(const float4*)&red[((0 * 4 + j) * 72 + ct) * 4];
                float4 o1 = *(const float4*)&red[((1 * 4 + j) * 72 + ct) * 4];
                float4 o2 = *(const float4*)&red[((2 * 4 + j) * 72 + ct) * 4];
                y[j][0] = gelu_exact(a[j][0] + o0.x + o1.x + o2.x) + hs[0][c + j];
                y[j][1] = gelu_exact(a[j][1] + o0.y + o1.y + o2.y) + hs[1][c + j];
                y[j][2] = gelu_exact(a[j][2] + o0.z + o1.z + o2.z) + hs[2][c + j];
                y[j][3] = gelu_exact(a[j][3] + o0.w + o1.w + o2.w) + hs[3][c + j];
            }
#pragma unroll
            for (int r = 0; r < 4; r++)
                *(float4*)&ys[r][c] = make_float4(y[0][r], y[1][r], y[2][r], y[3][r]);
        }
    }
    __syncthreads();

    // phase 3: LN2 (waves 0..3, one row each)
    const int w = tid >> 6;
    const int lane = tid & 63;
    if (w < 4) {
        const int r = w;
        float s = 0.f, ss = 0.f;
#pragma unroll
        for (int i = 0; i < 5; i++) {
            int j = lane + i * 64;
            if (j < D_) { float y = ys[r][j]; s += y; ss += y * y; }
        }
#pragma unroll
        for (int off = 32; off; off >>= 1) {
            s += __shfl_xor(s, off);
            ss += __shfl_xor(ss, off);
        }
        float mu = s * (1.0f / D_);
        float var = ss * (1.0f / D_) - mu * mu;
        float rstd = rsqrtf(var + EPS_);
        int row = base + r;
#pragma unroll
        for (int i = 0; i < 5; i++) {
            int j = lane + i * 64;
            if (j < D_) out[(size_t)row * D_ + j] = (ys[r][j] - mu) * rstd * g[j] + bb[j];
        }
    }
}

// ---------------------------------------------------------------------------
// K9-fallback: FFN layer 1, 3 cols/thread. grid 250, block 192.
// ---------------------------------------------------------------------------
__global__ __launch_bounds__(192) void ffn1_kernel(
    const float* __restrict__ h1,
    const float* __restrict__ W1, const float* __restrict__ b1,
    float* __restrict__ f1)
{
    constexpr int R = 8;
    __shared__ float hs[R][D_];
    const int base = blockIdx.x * R;
    const int tid = threadIdx.x;

    const float4* hsrc = (const float4*)(h1 + (size_t)base * D_);
    float4* hdst = (float4*)&hs[0][0];
    for (int i = tid; i < R * D_ / 4; i += 192) hdst[i] = hsrc[i];
    __syncthreads();

    const int j0 = tid, j1 = tid + 192, j2 = tid + 384;
    const float4* w0 = (const float4*)(W1 + (size_t)j0 * D_);
    const float4* w1 = (const float4*)(W1 + (size_t)j1 * D_);
    const float4* w2 = (const float4*)(W1 + (size_t)j2 * D_);
    float a0[R], a1[R], a2[R];
    float bb0 = b1[j0], bb1 = b1[j1], bb2 = b1[j2];
#pragma unroll
    for (int r = 0; r < R; r++) { a0[r] = bb0; a1[r] = bb1; a2[r] = bb2; }

    for (int d4 = 0; d4 < D_ / 4; d4++) {
        float4 x0 = w0[d4], x1 = w1[d4], x2 = w2[d4];
#pragma unroll
        for (int r = 0; r < R; r++) {
            float4 hv = *(const float4*)&hs[r][d4 * 4];
            a0[r] += dot4(hv, x0);
            a1[r] += dot4(hv, x1);
            a2[r] += dot4(hv, x2);
        }
    }
#pragma unroll
    for (int r = 0; r < R; r++) {
        size_t rowo = (size_t)(base + r) * DFF_;
        f1[rowo + j0] = gelu_exact(a0[r]);
        f1[rowo + j1] = gelu_exact(a1[r]);
        f1[rowo + j2] = gelu_exact(a2[r]);
    }
}

// ---------------------------------------------------------------------------
// K10-fallback: FFN layer 2 + residual + LN2 (non-transposed).
// ---------------------------------------------------------------------------
__global__ __launch_bounds__(320) void ffn2_ln_kernel(
    const float* __restrict__ f1, const float* __restrict__ h1,
    const float* __restrict__ W2, const float* __restrict__ b2,
    const float* __restrict__ g, const float* __restrict__ bb,
    float* __restrict__ out)
{
    constexpr int R = 8;
    __shared__ float fs[R][DFF_];
    __shared__ float hs[R][D_];
    __shared__ float ys[R][D_];
    const int base = blockIdx.x * R;
    const int tid = threadIdx.x;

    const float4* fsrc = (const float4*)(f1 + (size_t)base * DFF_);
    float4* fdst = (float4*)&fs[0][0];
    for (int i = tid; i < R * DFF_ / 4; i += 320) fdst[i] = fsrc[i];
    const float4* hsrc = (const float4*)(h1 + (size_t)base * D_);
    float4* hdst = (float4*)&hs[0][0];
    for (int i = tid; i < R * D_ / 4; i += 320) hdst[i] = hsrc[i];
    __syncthreads();

    if (tid < D_) {
        const float4* w4 = (const float4*)(W2 + (size_t)tid * DFF_);
        float acc[R];
        float bias = b2[tid];
#pragma unroll
        for (int r = 0; r < R; r++) acc[r] = bias;
        for (int d4 = 0; d4 < DFF_ / 4; d4++) {
            float4 wv = w4[d4];
#pragma unroll
            for (int r = 0; r < R; r++) {
                float4 fv = *(const float4*)&fs[r][d4 * 4];
                acc[r] += dot4(fv, wv);
            }
        }
#pragma unroll
        for (int r = 0; r < R; r++) ys[r][tid] = gelu_exact(acc[r]) + hs[r][tid];
    }
    __syncthreads();

    const int w = tid >> 6;
    const int lane = tid & 63;
    for (int r = w; r < R; r += 5) {
        float s = 0.f, ss = 0.f;
#pragma unroll
        for (int i = 0; i < 5; i++) {
            int j = lane + i * 64;
            if (j < D_) { float y = ys[r][j]; s += y; ss += y * y; }
        }
#pragma unroll
        for (int off = 32; off; off >>= 1) {
            s += __shfl_xor(s, off);
            ss += __shfl_xor(ss, off);
        }
        float mu = s * (1.0f / D_);
        float var = ss * (1.0f / D_) - mu * mu;
        float rstd = rsqrtf(var + EPS_);
        int row = base + r;
#pragma unroll
        for (int i = 0; i < 5; i++) {
            int j = lane + i * 64;
            if (j < D_) out[(size_t)row * D_ + j] = (ys[r][j] - mu) * rstd * g[j] + bb[j];
        }
    }
}

// ---------------------------------------------------------------------------
extern "C" void kernel_launch(void* const* d_in, const int* in_sizes, int n_in,
                              void* d_out, int out_size, void* d_ws, size_t ws_size,
                              hipStream_t stream)
{
    const float* x         = (const float*)d_in[0];
    const int*   index_key = (const int*)  d_in[1];
    const float* Wq = (const float*)d_in[2];
    const float* bq = (const float*)d_in[3];
    const float* Wk = (const float*)d_in[4];
    const float* bk = (const float*)d_in[5];
    const float* Wv = (const float*)d_in[6];
    const float* bv = (const float*)d_in[7];
    const float* W1 = (const float*)d_in[8];
    const float* b1 = (const float*)d_in[9];
    const float* W2 = (const float*)d_in[10];
    const float* b2 = (const float*)d_in[11];
    const float* ln1_g = (const float*)d_in[12];
    const float* ln1_b = (const float*)d_in[13];
    const float* ln2_g = (const float*)d_in[14];
    const float* ln2_b = (const float*)d_in[15];
    float* out = (float*)d_out;

    // workspace carve (floats)
    float* Q        = (float*)d_ws;                      // 576000
    float* K        = Q + 576000;
    float* V        = K + 576000;
    float* Vmean    = V + 576000;                        // 576
    float* measure  = Vmean + 576;                       // 16000
    float* attn_out = measure + 16000;                   // 576000
    float* h1       = attn_out + 576000;                 // 576000
    int*   qlist    = (int*)(h1 + 576000);               // 4000 ints
    int*   slot_map = qlist + 4000;                      // 16000 ints
    float* part     = (float*)(slot_map + 16000);        // 4,000,000
    float* f1       = part;                              // fallback only
    float* KT       = part + 4000000;                    // 576,000

    // transposed weights alias the part region when it's dead:
    float* WqT = part;                                   // dead before attn_part
    float* WkT = WqT + 82944;
    float* WvT = WkT + 82944;
    float* W1T = part;                                   // part dead after combine_all
    float* W2T = part + 165888;

    const size_t kt_end = 2916576ull + 4000000ull + 576000ull;  // ~30 MB
    const bool   big    = ws_size >= kt_end * sizeof(float);
    const int    nchunk = big ? 25 : 8;
    const int    chunk_len = L_ / nchunk;

    if (big) {
        qkv_transpose_kernel<<<243, 256, 0, stream>>>(Wq, Wk, Wv, WqT, WkT, WvT);
        qkvT2_kernel<<<500, 256, 0, stream>>>(x, WqT, WkT, WvT, bq, bk, bv, Q, K, V);
    } else {
        qkv_kernel<<<250, 320, 0, stream>>>(x, Wq, bq, Wk, bk, Wv, bv, Q, K, V);
    }
    vmean_kernel<<<BH_, 256, 0, stream>>>(V, Vmean);
    if (big) {
        ktranspose_kernel<<<BH_ * 64, 256, 0, stream>>>(K, KT);
        score_measure3_kernel<<<BH_ * 125, 256, 0, stream>>>(Q, KT, index_key, measure);
    } else {
        measure_kernel<<<4000, 256, 0, stream>>>(Q, K, index_key, measure);
    }
    topk2_kernel<<<BH_, 1024, 0, stream>>>(measure, qlist, slot_map);
    attn_part_kernel<<<BH_ * nchunk, 256, 0, stream>>>(Q, K, V, qlist, part, nchunk, chunk_len);
    combine_all_kernel<<<(B_ * L_ * D_ + 255) / 256, 256, 0, stream>>>(
        part, slot_map, Vmean, attn_out, nchunk);
    ln1_kernel<<<B_ * L_, 64, 0, stream>>>(x, attn_out, ln1_g, ln1_b, h1);
    if (big) {
        ffn_transpose_kernel<<<324, 256, 0, stream>>>(W1, W2, W1T, W2T);
        ffn_fused2b_kernel<<<500, 288, 0, stream>>>(h1, W1T, b1, W2T, b2, ln2_g, ln2_b, out);
    } else {
        ffn1_kernel<<<250, 192, 0, stream>>>(h1, W1, b1, f1);
        ffn2_ln_kernel<<<250, 320, 0, stream>>>(f1, h1, W2, b2, ln2_g, ln2_b, out);
    }
}

// Round 18
// 299.967 us; speedup vs baseline: 1.0447x; 1.0447x over previous
//
#include <hip/hip_runtime.h>
#include <hip/hip_bf16.h>
#include <math.h>

// Problem constants
#define B_ 2
#define L_ 1000
#define D_ 288
#define H_ 8
#define DIM_ 36
#define DFF_ 576
#define KS_ 250
#define NQ_ 250
#define BH_ (B_ * H_)
#define EPS_ 1e-5f
#define PSTRIDE_ 40             // partial row: 36 acc + 1 sum, padded to 40

__device__ __forceinline__ float gelu_exact(float x) {
    return 0.5f * x * (1.0f + erff(x * 0.70710678118654752f));
}

__device__ __forceinline__ float dot4(float4 a, float4 b) {
    return a.x * b.x + a.y * b.y + a.z * b.z + a.w * b.w;
}

// ---------------------------------------------------------------------------
// K0a: merged QKV weight transpose (3 x 288x288 in one launch). grid 243.
// ---------------------------------------------------------------------------
__global__ __launch_bounds__(256) void qkv_transpose_kernel(
    const float* __restrict__ Wq, const float* __restrict__ Wk,
    const float* __restrict__ Wv,
    float* __restrict__ WqT, float* __restrict__ WkT, float* __restrict__ WvT)
{
    __shared__ float tile[32][33];
    const int m = blockIdx.x / 81;
    const int t = blockIdx.x % 81;
    const float* src = (m == 0) ? Wq : (m == 1) ? Wk : Wv;
    float* dst = (m == 0) ? WqT : (m == 1) ? WkT : WvT;
    const int ty0 = (t / 9) * 32, tx0 = (t % 9) * 32;
    const int tx = threadIdx.x & 31, ty = threadIdx.x >> 5;
#pragma unroll
    for (int i = 0; i < 4; i++)
        tile[ty + 8 * i][tx] = src[(size_t)(ty0 + ty + 8 * i) * D_ + tx0 + tx];
    __syncthreads();
#pragma unroll
    for (int i = 0; i < 4; i++)
        dst[(size_t)(tx0 + ty + 8 * i) * D_ + ty0 + tx] = tile[tx][ty + 8 * i];
}

// ---------------------------------------------------------------------------
// K0c: merged FFN weight transpose: W1[576][288]->W1T, W2[288][576]->W2T.
// grid 324 (162 tiles each).
// ---------------------------------------------------------------------------
__global__ __launch_bounds__(256) void ffn_transpose_kernel(
    const float* __restrict__ W1, const float* __restrict__ W2,
    float* __restrict__ W1T, float* __restrict__ W2T)
{
    __shared__ float tile[32][33];
    int t = blockIdx.x;
    const float* src; float* dst; int Rr, Cc, ntx;
    if (t < 162) { src = W1; dst = W1T; Rr = DFF_; Cc = D_; ntx = 9; }
    else { t -= 162; src = W2; dst = W2T; Rr = D_; Cc = DFF_; ntx = 18; }
    const int ty0 = (t / ntx) * 32, tx0 = (t % ntx) * 32;
    const int tx = threadIdx.x & 31, ty = threadIdx.x >> 5;
#pragma unroll
    for (int i = 0; i < 4; i++)
        tile[ty + 8 * i][tx] = src[(size_t)(ty0 + ty + 8 * i) * Cc + tx0 + tx];
    __syncthreads();
#pragma unroll
    for (int i = 0; i < 4; i++)
        dst[(size_t)(tx0 + ty + 8 * i) * Rr + ty0 + tx] = tile[tx][ty + 8 * i];
}

// ---------------------------------------------------------------------------
// K0b: batched K transpose: K[bh][l][d] -> KT[bh][d][l]. grid 1024.
// ---------------------------------------------------------------------------
__global__ __launch_bounds__(256) void ktranspose_kernel(
    const float* __restrict__ K, float* __restrict__ KT)
{
    __shared__ float tile[32][33];
    const int t = blockIdx.x;
    const int bh = t >> 6;
    const int rem = t & 63;
    const int lt = rem >> 1, dt = rem & 1;
    const int l0 = lt * 32, d0 = dt * 32;
    const int tx = threadIdx.x & 31, ty = threadIdx.x >> 5;
    const float* Kb = K + (size_t)bh * L_ * DIM_;
    float* KTb = KT + (size_t)bh * DIM_ * L_;
#pragma unroll
    for (int i = 0; i < 4; i++) {
        int l = l0 + ty + 8 * i, d = d0 + tx;
        tile[ty + 8 * i][tx] = (l < L_ && d < DIM_) ? Kb[(size_t)l * DIM_ + d] : 0.f;
    }
    __syncthreads();
#pragma unroll
    for (int i = 0; i < 4; i++) {
        int d = d0 + ty + 8 * i, l = l0 + tx;
        if (d < DIM_ && l < L_) KTb[(size_t)d * L_ + l] = tile[tx][ty + 8 * i];
    }
}

// ---------------------------------------------------------------------------
// K1: QKV: register-tiled 4 cols x 4 rows. grid 500, block 256.
// ---------------------------------------------------------------------------
__global__ __launch_bounds__(256) void qkvT2_kernel(
    const float* __restrict__ x,
    const float* __restrict__ WqT, const float* __restrict__ WkT,
    const float* __restrict__ WvT,
    const float* __restrict__ bq, const float* __restrict__ bk,
    const float* __restrict__ bv,
    float* __restrict__ Q, float* __restrict__ K, float* __restrict__ V)
{
    __shared__ float xsT[D_][4];        // [k][r]
    const int base = blockIdx.x * 4;
    const int tid = threadIdx.x;

    for (int idx = tid; idx < 4 * D_; idx += 256) {
        int r = idx / D_, k = idx % D_;
        xsT[k][r] = x[(size_t)(base + r) * D_ + k];
    }
    __syncthreads();

    if (tid < 216) {
        const int gcol = 4 * tid;              // 0..863
        const int m = gcol / D_;
        const int c = gcol - m * D_;
        const float* WT = (m == 0) ? WqT : (m == 1) ? WkT : WvT;
        const float* bias = (m == 0) ? bq : (m == 1) ? bk : bv;
        float* outp = (m == 0) ? Q : (m == 1) ? K : V;

        float a[4][4];
#pragma unroll
        for (int j = 0; j < 4; j++) {
            float bv2 = bias[c + j];
#pragma unroll
            for (int r = 0; r < 4; r++) a[j][r] = bv2;
        }

        for (int k = 0; k < D_; k++) {
            float4 w = *(const float4*)(WT + (size_t)k * D_ + c);
            float4 xv = *(const float4*)&xsT[k][0];
            a[0][0] += w.x * xv.x; a[0][1] += w.x * xv.y; a[0][2] += w.x * xv.z; a[0][3] += w.x * xv.w;
            a[1][0] += w.y * xv.x; a[1][1] += w.y * xv.y; a[1][2] += w.y * xv.z; a[1][3] += w.y * xv.w;
            a[2][0] += w.z * xv.x; a[2][1] += w.z * xv.y; a[2][2] += w.z * xv.z; a[2][3] += w.z * xv.w;
            a[3][0] += w.w * xv.x; a[3][1] += w.w * xv.y; a[3][2] += w.w * xv.z; a[3][3] += w.w * xv.w;
        }

#pragma unroll
        for (int j = 0; j < 4; j++) {
            int col = c + j;
            int h = col / DIM_, dd = col % DIM_;
#pragma unroll
            for (int r = 0; r < 4; r++) {
                int row = base + r;
                int b = row / L_, l = row % L_;
                outp[((size_t)(b * H_ + h) * L_ + l) * DIM_ + dd] = a[j][r];
            }
        }
    }
}

// ---------------------------------------------------------------------------
// K1-fallback: qkv with row-major weights.
// ---------------------------------------------------------------------------
__global__ __launch_bounds__(320) void qkv_kernel(
    const float* __restrict__ x,
    const float* __restrict__ Wq, const float* __restrict__ bq,
    const float* __restrict__ Wk, const float* __restrict__ bk,
    const float* __restrict__ Wv, const float* __restrict__ bv,
    float* __restrict__ Q, float* __restrict__ K, float* __restrict__ V)
{
    constexpr int R = 8;
    __shared__ float xs[R][D_];
    const int base = blockIdx.x * R;
    const int tid = threadIdx.x;

    const float4* xsrc = (const float4*)(x + (size_t)base * D_);
    float4* xdst = (float4*)&xs[0][0];
    for (int i = tid; i < R * D_ / 4; i += 320) xdst[i] = xsrc[i];
    __syncthreads();

    if (tid < D_) {
        const float4* wq4 = (const float4*)(Wq + (size_t)tid * D_);
        const float4* wk4 = (const float4*)(Wk + (size_t)tid * D_);
        const float4* wv4 = (const float4*)(Wv + (size_t)tid * D_);
        float aq[R], ak[R], av[R];
        float biasq = bq[tid], biask = bk[tid], biasv = bv[tid];
#pragma unroll
        for (int r = 0; r < R; r++) { aq[r] = biasq; ak[r] = biask; av[r] = biasv; }
        for (int d4 = 0; d4 < D_ / 4; d4++) {
            float4 wqv = wq4[d4], wkv = wk4[d4], wvv = wv4[d4];
#pragma unroll
            for (int r = 0; r < R; r++) {
                float4 hv = *(const float4*)&xs[r][d4 * 4];
                aq[r] += dot4(hv, wqv);
                ak[r] += dot4(hv, wkv);
                av[r] += dot4(hv, wvv);
            }
        }
        const int h = tid / DIM_, dd = tid % DIM_;
#pragma unroll
        for (int r = 0; r < R; r++) {
            int row = base + r;
            int b = row / L_, l = row % L_;
            size_t o = ((size_t)(b * H_ + h) * L_ + l) * DIM_ + dd;
            Q[o] = aq[r]; K[o] = ak[r]; V[o] = av[r];
        }
    }
}

// ---------------------------------------------------------------------------
// K2: Vmean[bh, d]. Block per bh.
// ---------------------------------------------------------------------------
__global__ __launch_bounds__(256) void vmean_kernel(
    const float* __restrict__ V, float* __restrict__ Vmean)
{
    const int bh = blockIdx.x;
    const int tid = threadIdx.x;
    __shared__ float red[7][DIM_];
    if (tid < 252) {
        int g = tid / DIM_, d = tid % DIM_;
        const float* base = V + (size_t)bh * L_ * DIM_;
        float s = 0.f;
        for (int l = g; l < L_; l += 7) s += base[l * DIM_ + d];
        red[g][d] = s;
    }
    __syncthreads();
    if (tid < DIM_) {
        float s = 0.f;
#pragma unroll
        for (int g = 0; g < 7; g++) s += red[g][tid];
        Vmean[bh * DIM_ + tid] = s * (1.0f / L_);
    }
}

// ---------------------------------------------------------------------------
// K3: FUSED score+measure: KT coalesced scalar loads (lane = key),
// acc[8] register shape. grid 2000, block 256.
// ---------------------------------------------------------------------------
__global__ __launch_bounds__(256) void score_measure3_kernel(
    const float* __restrict__ Q, const float* __restrict__ KT,
    const int* __restrict__ index_key, float* __restrict__ measure)
{
    constexpr int R = 8;
    __shared__ float qs[R][DIM_];
    __shared__ float st[R][1004];
    const int bh = blockIdx.x / 125;
    const int qt = blockIdx.x % 125;
    const int tid = threadIdx.x;

    if (tid < R * DIM_ / 4)
        ((float4*)&qs[0][0])[tid] =
            ((const float4*)(Q + ((size_t)bh * L_ + qt * R) * DIM_))[tid];
    __syncthreads();

    const float* KTb = KT + (size_t)bh * DIM_ * L_;
#pragma unroll
    for (int i = 0; i < 4; i++) {
        const int k = i * 256 + tid;
        if (k < L_) {
            float acc[R];
#pragma unroll
            for (int r = 0; r < R; r++) acc[r] = 0.f;
#pragma unroll
            for (int d4 = 0; d4 < DIM_ / 4; d4++) {
                float4 kv;
                kv.x = KTb[(size_t)(d4 * 4 + 0) * L_ + k];
                kv.y = KTb[(size_t)(d4 * 4 + 1) * L_ + k];
                kv.z = KTb[(size_t)(d4 * 4 + 2) * L_ + k];
                kv.w = KTb[(size_t)(d4 * 4 + 3) * L_ + k];
#pragma unroll
                for (int r = 0; r < R; r++)
                    acc[r] += dot4(*(const float4*)&qs[r][d4 * 4], kv);
            }
#pragma unroll
            for (int r = 0; r < R; r++) st[r][k] = acc[r];
        }
    }
    __syncthreads();

    // measure: lane-group of 32 per query
    const int r = tid >> 5;             // 0..7
    const int lane = tid & 31;
    const int l = qt * R + r;
    const int* ik = index_key + l * KS_;
    float mx = -1e30f, sm = 0.f;
    for (int s = lane; s < KS_; s += 32) {
        float v = st[r][ik[s]];
        mx = fmaxf(mx, v);
        sm += v;
    }
#pragma unroll
    for (int off = 16; off; off >>= 1) {
        mx = fmaxf(mx, __shfl_xor(mx, off));
        sm += __shfl_xor(sm, off);
    }
    if (lane == 0) measure[bh * L_ + l] = mx - sm * (1.0f / (float)L_);
}

// ---------------------------------------------------------------------------
// K3-fallback: gather-based measure.
// ---------------------------------------------------------------------------
__global__ __launch_bounds__(256) void measure_kernel(
    const float* __restrict__ Q, const float* __restrict__ K,
    const int* __restrict__ index_key, float* __restrict__ measure)
{
    const int w = threadIdx.x >> 6;
    const int lane = threadIdx.x & 63;
    const int wid = blockIdx.x * 4 + w;
    const int bh = wid / L_;
    const int l = wid % L_;

    const float4* qp = (const float4*)(Q + ((size_t)bh * L_ + l) * DIM_);
    float4 q[9];
#pragma unroll
    for (int i = 0; i < 9; i++) q[i] = qp[i];

    const int* ik = index_key + l * KS_;
    const float* Kb = K + (size_t)bh * L_ * DIM_;

    float mx = -1e30f, sm = 0.f;
#pragma unroll
    for (int s = lane; s < KS_; s += 64) {
        int kidx = ik[s];
        const float4* k4 = (const float4*)(Kb + (size_t)kidx * DIM_);
        float acc = 0.f;
#pragma unroll
        for (int i = 0; i < 9; i++) acc += dot4(q[i], k4[i]);
        mx = fmaxf(mx, acc);
        sm += acc;
    }
#pragma unroll
    for (int off = 32; off; off >>= 1) {
        mx = fmaxf(mx, __shfl_xor(mx, off));
        sm += __shfl_xor(sm, off);
    }
    if (lane == 0) measure[wid] = mx - sm * (1.0f / (float)L_);
}

// ---------------------------------------------------------------------------
// K4: top-NQ rank-based, grid 64 (bh x quarter), block 256. Rank IS the
// slot (deterministic, matches lax.top_k stable order). No atomics, no
// memset: every l gets slot_map written by its owning thread.
// ---------------------------------------------------------------------------
__global__ __launch_bounds__(256) void topk_rank_kernel(
    const float* __restrict__ measure, int* __restrict__ qlist,
    int* __restrict__ slot_map)
{
    const int bh = blockIdx.x >> 2;
    const int quarter = blockIdx.x & 3;
    __shared__ float m[L_];
    for (int i = threadIdx.x; i < L_; i += 256) m[i] = measure[bh * L_ + i];
    __syncthreads();
    const int i = quarter * 250 + threadIdx.x;
    if (threadIdx.x < 250) {
        float mi = m[i];
        int rank = 0;
        for (int j = 0; j < L_; j++) {
            float mj = m[j];
            rank += (mj > mi) || (mj == mi && j < i);
        }
        if (rank < NQ_) qlist[bh * NQ_ + rank] = i;
        slot_map[bh * L_ + i] = (rank < NQ_) ? rank : -1;
    }
}

// ---------------------------------------------------------------------------
// K6: attention partials via K-dot recompute, wave-uniform K/V loads.
// grid BH_*nchunk, block 256 (250 active).
// ---------------------------------------------------------------------------
__global__ __launch_bounds__(256) void attn_part_kernel(
    const float* __restrict__ Q, const float* __restrict__ K,
    const float* __restrict__ V, const int* __restrict__ qlist,
    float* __restrict__ part, int nchunk, int chunk_len)
{
    const int bh = blockIdx.x / nchunk;
    const int chunk = blockIdx.x % nchunk;
    const int slot = threadIdx.x;
    if (slot >= NQ_) return;

    const int qidx = qlist[bh * NQ_ + slot];
    const float4* qp = (const float4*)(Q + ((size_t)bh * L_ + qidx) * DIM_);
    float4 q[9];
#pragma unroll
    for (int i = 0; i < 9; i++) q[i] = qp[i];

    const float* Kb = K + (size_t)bh * L_ * DIM_;
    const float* Vb = V + (size_t)bh * L_ * DIM_;
    const float scale = (float)(1.0 / 6.0);

    float4 acc[9];
#pragma unroll
    for (int i = 0; i < 9; i++) acc[i] = make_float4(0.f, 0.f, 0.f, 0.f);
    float sum = 0.f;

    const int k0 = chunk * chunk_len;
    for (int j = 0; j < chunk_len; j++) {
        const int key = k0 + j;                       // wave-uniform
        const float4* kp = (const float4*)(Kb + (size_t)key * DIM_);
        float s = 0.f;
#pragma unroll
        for (int i = 0; i < 9; i++) s += dot4(q[i], kp[i]);
        float e = __expf(s * scale);
        sum += e;
        const float4* vp = (const float4*)(Vb + (size_t)key * DIM_);
#pragma unroll
        for (int i = 0; i < 9; i++) {
            float4 vv = vp[i];
            acc[i].x += e * vv.x;
            acc[i].y += e * vv.y;
            acc[i].z += e * vv.z;
            acc[i].w += e * vv.w;
        }
    }

    float* p = part + ((size_t)(bh * NQ_ + slot) * nchunk + chunk) * PSTRIDE_;
#pragma unroll
    for (int i = 0; i < 9; i++) ((float4*)p)[i] = acc[i];
    p[DIM_] = sum;
}

// ---------------------------------------------------------------------------
// K7: combine_all: one thread per (b,l,d-full). Lazy rows take Vmean;
// selected reduce chunk partials. grid 2250, block 256.
// ---------------------------------------------------------------------------
__global__ __launch_bounds__(256) void combine_all_kernel(
    const float* __restrict__ part, const int* __restrict__ slot_map,
    const float* __restrict__ Vmean, float* __restrict__ attn_out, int nchunk)
{
    int idx = blockIdx.x * blockDim.x + threadIdx.x;
    if (idx >= B_ * L_ * D_) return;
    int dfull = idx % D_;
    int bl = idx / D_;
    int b = bl / L_, l = bl % L_;
    int h = dfull / DIM_, d = dfull % DIM_;
    int bh = b * H_ + h;
    int slot = slot_map[bh * L_ + l];
    float v;
    if (slot < 0) {
        v = Vmean[bh * DIM_ + d];
    } else {
        const float* p = part + (size_t)(bh * NQ_ + slot) * nchunk * PSTRIDE_;
        float a = 0.f, s = 0.f;
        for (int c = 0; c < nchunk; c++) {
            a += p[c * PSTRIDE_ + d];
            s += p[c * PSTRIDE_ + DIM_];
        }
        v = a / s;
    }
    attn_out[idx] = v;
}

// ---------------------------------------------------------------------------
// K8: LN1: h1 = LayerNorm(x + attn_out). One wave per row.
// ---------------------------------------------------------------------------
__global__ __launch_bounds__(64) void ln1_kernel(
    const float* __restrict__ x, const float* __restrict__ attn,
    const float* __restrict__ g, const float* __restrict__ bb,
    float* __restrict__ h1)
{
    const int row = blockIdx.x;
    const int lane = threadIdx.x;
    const float* xr = x + (size_t)row * D_;
    const float* ar = attn + (size_t)row * D_;

    float vals[5];
    float s = 0.f;
#pragma unroll
    for (int i = 0; i < 5; i++) {
        int j = lane + i * 64;
        float v = (j < D_) ? (xr[j] + ar[j]) : 0.f;
        vals[i] = v;
        s += v;
    }
#pragma unroll
    for (int off = 32; off; off >>= 1) s += __shfl_xor(s, off);
    float mu = s * (1.0f / D_);

    float vs = 0.f;
#pragma unroll
    for (int i = 0; i < 5; i++) {
        int j = lane + i * 64;
        if (j < D_) { float dd = vals[i] - mu; vs += dd * dd; }
    }
#pragma unroll
    for (int off = 32; off; off >>= 1) vs += __shfl_xor(vs, off);
    float rstd = rsqrtf(vs * (1.0f / D_) + EPS_);

#pragma unroll
    for (int i = 0; i < 5; i++) {
        int j = lane + i * 64;
        if (j < D_) h1[(size_t)row * D_ + j] = (vals[i] - mu) * rstd * g[j] + bb[j];
    }
}

// ---------------------------------------------------------------------------
// K9: FUSED FFN v2b (R16): conflict-free LDS layouts. grid 500, block 288.
// ---------------------------------------------------------------------------
__global__ __launch_bounds__(288) void ffn_fused2b_kernel(
    const float* __restrict__ h1,
    const float* __restrict__ W1T, const float* __restrict__ b1,
    const float* __restrict__ W2T, const float* __restrict__ b2,
    const float* __restrict__ g, const float* __restrict__ bb,
    float* __restrict__ out)
{
    __shared__ float hs[4][D_];
    __shared__ float fs[4][DFF_];
    __shared__ float red[3456];
    __shared__ float ys[4][D_];
    const int base = blockIdx.x * 4;
    const int tid = threadIdx.x;

    {
        const float4* src = (const float4*)(h1 + (size_t)base * D_);
        float4* dst = (float4*)&hs[0][0];
        for (int i = tid; i < 4 * D_ / 4; i += 288) dst[i] = src[i];
    }
    __syncthreads();

    // phase 1: f = gelu(h1 @ W1T + b1), 2-way k-split
    {
        const int kg = tid / 144;
        const int ct = tid - kg * 144;
        const int c = 4 * ct;
        float a[4][4];
        if (kg == 0) {
#pragma unroll
            for (int j = 0; j < 4; j++) {
                float bv = b1[c + j];
#pragma unroll
                for (int r = 0; r < 4; r++) a[j][r] = bv;
            }
        } else {
#pragma unroll
            for (int j = 0; j < 4; j++)
#pragma unroll
                for (int r = 0; r < 4; r++) a[j][r] = 0.f;
        }
        const int kbeg = kg * 144;
        for (int k = kbeg; k < kbeg + 144; k++) {
            float4 w = *(const float4*)(W1T + (size_t)k * DFF_ + c);
            float x0 = hs[0][k], x1 = hs[1][k], x2 = hs[2][k], x3 = hs[3][k];
            a[0][0] += w.x * x0; a[0][1] += w.x * x1; a[0][2] += w.x * x2; a[0][3] += w.x * x3;
            a[1][0] += w.y * x0; a[1][1] += w.y * x1; a[1][2] += w.y * x2; a[1][3] += w.y * x3;
            a[2][0] += w.z * x0; a[2][1] += w.z * x1; a[2][2] += w.z * x2; a[2][3] += w.z * x3;
            a[3][0] += w.w * x0; a[3][1] += w.w * x1; a[3][2] += w.w * x2; a[3][3] += w.w * x3;
        }
        if (kg == 1) {
#pragma unroll
            for (int j = 0; j < 4; j++)
                *(float4*)&red[(j * 144 + ct) * 4] =
                    make_float4(a[j][0], a[j][1], a[j][2], a[j][3]);
        }
        __syncthreads();
        if (kg == 0) {
            float y[4][4];
#pragma unroll
            for (int j = 0; j < 4; j++) {
                float4 o = *(const float4*)&red[(j * 144 + ct) * 4];
                y[j][0] = gelu_exact(a[j][0] + o.x);
                y[j][1] = gelu_exact(a[j][1] + o.y);
                y[j][2] = gelu_exact(a[j][2] + o.z);
                y[j][3] = gelu_exact(a[j][3] + o.w);
            }
#pragma unroll
            for (int r = 0; r < 4; r++)
                *(float4*)&fs[r][c] = make_float4(y[0][r], y[1][r], y[2][r], y[3][r]);
        }
    }
    __syncthreads();

    // phase 2: y = gelu(f @ W2T + b2) + h1, 4-way k-split
    {
        const int kg = tid / 72;
        const int ct = tid - kg * 72;
        const int c = 4 * ct;
        float a[4][4];
        if (kg == 0) {
#pragma unroll
            for (int j = 0; j < 4; j++) {
                float bv = b2[c + j];
#pragma unroll
                for (int r = 0; r < 4; r++) a[j][r] = bv;
            }
        } else {
#pragma unroll
            for (int j = 0; j < 4; j++)
#pragma unroll
                for (int r = 0; r < 4; r++) a[j][r] = 0.f;
        }
        const int kbeg = kg * 144;
        for (int k = kbeg; k < kbeg + 144; k++) {
            float4 w = *(const float4*)(W2T + (size_t)k * D_ + c);
            float f0 = fs[0][k], f1 = fs[1][k], f2 = fs[2][k], f3 = fs[3][k];
            a[0][0] += w.x * f0; a[0][1] += w.x * f1; a[0][2] += w.x * f2; a[0][3] += w.x * f3;
            a[1][0] += w.y * f0; a[1][1] += w.y * f1; a[1][2] += w.y * f2; a[1][3] += w.y * f3;
            a[2][0] += w.z * f0; a[2][1] += w.z * f1; a[2][2] += w.z * f2; a[2][3] += w.z * f3;
            a[3][0] += w.w * f0; a[3][1] += w.w * f1; a[3][2] += w.w * f2; a[3][3] += w.w * f3;
        }
        if (kg >= 1) {
#pragma unroll
            for (int j = 0; j < 4; j++)
                *(float4*)&red[(((kg - 1) * 4 + j) * 72 + ct) * 4] =
                    make_float4(a[j][0], a[j][1], a[j][2], a[j][3]);
        }
        __syncthreads();
        if (kg == 0) {
            float y[4][4];
#pragma unroll
            for (int j = 0; j < 4; j++) {
                float4 o0 = *(const float4*)&red[((0 * 4 + j) * 72 + ct) * 4];
                float4 o1 = *(const float4*)&red[((1 * 4 + j) * 72 + ct) * 4];
                float4 o2 = *(const float4*)&red[((2 * 4 + j) * 72 + ct) * 4];
                y[j][0] = gelu_exact(a[j][0] + o0.x + o1.x + o2.x) + hs[0][c + j];
                y[j][1] = gelu_exact(a[j][1] + o0.y + o1.y + o2.y) + hs[1][c + j];
                y[j][2] = gelu_exact(a[j][2] + o0.z + o1.z + o2.z) + hs[2][c + j];
                y[j][3] = gelu_exact(a[j][3] + o0.w + o1.w + o2.w) + hs[3][c + j];
            }
#pragma unroll
            for (int r = 0; r < 4; r++)
                *(float4*)&ys[r][c] = make_float4(y[0][r], y[1][r], y[2][r], y[3][r]);
        }
    }
    __syncthreads();

    // phase 3: LN2 (waves 0..3, one row each)
    const int w = tid >> 6;
    const int lane = tid & 63;
    if (w < 4) {
        const int r = w;
        float s = 0.f, ss = 0.f;
#pragma unroll
        for (int i = 0; i < 5; i++) {
            int j = lane + i * 64;
            if (j < D_) { float y = ys[r][j]; s += y; ss += y * y; }
        }
#pragma unroll
        for (int off = 32; off; off >>= 1) {
            s += __shfl_xor(s, off);
            ss += __shfl_xor(ss, off);
        }
        float mu = s * (1.0f / D_);
        float var = ss * (1.0f / D_) - mu * mu;
        float rstd = rsqrtf(var + EPS_);
        int row = base + r;
#pragma unroll
        for (int i = 0; i < 5; i++) {
            int j = lane + i * 64;
            if (j < D_) out[(size_t)row * D_ + j] = (ys[r][j] - mu) * rstd * g[j] + bb[j];
        }
    }
}

// ---------------------------------------------------------------------------
// K9-fallback: FFN layer 1, 3 cols/thread. grid 250, block 192.
// ---------------------------------------------------------------------------
__global__ __launch_bounds__(192) void ffn1_kernel(
    const float* __restrict__ h1,
    const float* __restrict__ W1, const float* __restrict__ b1,
    float* __restrict__ f1)
{
    constexpr int R = 8;
    __shared__ float hs[R][D_];
    const int base = blockIdx.x * R;
    const int tid = threadIdx.x;

    const float4* hsrc = (const float4*)(h1 + (size_t)base * D_);
    float4* hdst = (float4*)&hs[0][0];
    for (int i = tid; i < R * D_ / 4; i += 192) hdst[i] = hsrc[i];
    __syncthreads();

    const int j0 = tid, j1 = tid + 192, j2 = tid + 384;
    const float4* w0 = (const float4*)(W1 + (size_t)j0 * D_);
    const float4* w1 = (const float4*)(W1 + (size_t)j1 * D_);
    const float4* w2 = (const float4*)(W1 + (size_t)j2 * D_);
    float a0[R], a1[R], a2[R];
    float bb0 = b1[j0], bb1 = b1[j1], bb2 = b1[j2];
#pragma unroll
    for (int r = 0; r < R; r++) { a0[r] = bb0; a1[r] = bb1; a2[r] = bb2; }

    for (int d4 = 0; d4 < D_ / 4; d4++) {
        float4 x0 = w0[d4], x1 = w1[d4], x2 = w2[d4];
#pragma unroll
        for (int r = 0; r < R; r++) {
            float4 hv = *(const float4*)&hs[r][d4 * 4];
            a0[r] += dot4(hv, x0);
            a1[r] += dot4(hv, x1);
            a2[r] += dot4(hv, x2);
        }
    }
#pragma unroll
    for (int r = 0; r < R; r++) {
        size_t rowo = (size_t)(base + r) * DFF_;
        f1[rowo + j0] = gelu_exact(a0[r]);
        f1[rowo + j1] = gelu_exact(a1[r]);
        f1[rowo + j2] = gelu_exact(a2[r]);
    }
}

// ---------------------------------------------------------------------------
// K10-fallback: FFN layer 2 + residual + LN2 (non-transposed).
// ---------------------------------------------------------------------------
__global__ __launch_bounds__(320) void ffn2_ln_kernel(
    const float* __restrict__ f1, const float* __restrict__ h1,
    const float* __restrict__ W2, const float* __restrict__ b2,
    const float* __restrict__ g, const float* __restrict__ bb,
    float* __restrict__ out)
{
    constexpr int R = 8;
    __shared__ float fs[R][DFF_];
    __shared__ float hs[R][D_];
    __shared__ float ys[R][D_];
    const int base = blockIdx.x * R;
    const int tid = threadIdx.x;

    const float4* fsrc = (const float4*)(f1 + (size_t)base * DFF_);
    float4* fdst = (float4*)&fs[0][0];
    for (int i = tid; i < R * DFF_ / 4; i += 320) fdst[i] = fsrc[i];
    const float4* hsrc = (const float4*)(h1 + (size_t)base * D_);
    float4* hdst = (float4*)&hs[0][0];
    for (int i = tid; i < R * D_ / 4; i += 320) hdst[i] = hsrc[i];
    __syncthreads();

    if (tid < D_) {
        const float4* w4 = (const float4*)(W2 + (size_t)tid * DFF_);
        float acc[R];
        float bias = b2[tid];
#pragma unroll
        for (int r = 0; r < R; r++) acc[r] = bias;
        for (int d4 = 0; d4 < DFF_ / 4; d4++) {
            float4 wv = w4[d4];
#pragma unroll
            for (int r = 0; r < R; r++) {
                float4 fv = *(const float4*)&fs[r][d4 * 4];
                acc[r] += dot4(fv, wv);
            }
        }
#pragma unroll
        for (int r = 0; r < R; r++) ys[r][tid] = gelu_exact(acc[r]) + hs[r][tid];
    }
    __syncthreads();

    const int w = tid >> 6;
    const int lane = tid & 63;
    for (int r = w; r < R; r += 5) {
        float s = 0.f, ss = 0.f;
#pragma unroll
        for (int i = 0; i < 5; i++) {
            int j = lane + i * 64;
            if (j < D_) { float y = ys[r][j]; s += y; ss += y * y; }
        }
#pragma unroll
        for (int off = 32; off; off >>= 1) {
            s += __shfl_xor(s, off);
            ss += __shfl_xor(ss, off);
        }
        float mu = s * (1.0f / D_);
        float var = ss * (1.0f / D_) - mu * mu;
        float rstd = rsqrtf(var + EPS_);
        int row = base + r;
#pragma unroll
        for (int i = 0; i < 5; i++) {
            int j = lane + i * 64;
            if (j < D_) out[(size_t)row * D_ + j] = (ys[r][j] - mu) * rstd * g[j] + bb[j];
        }
    }
}

// ---------------------------------------------------------------------------
extern "C" void kernel_launch(void* const* d_in, const int* in_sizes, int n_in,
                              void* d_out, int out_size, void* d_ws, size_t ws_size,
                              hipStream_t stream)
{
    const float* x         = (const float*)d_in[0];
    const int*   index_key = (const int*)  d_in[1];
    const float* Wq = (const float*)d_in[2];
    const float* bq = (const float*)d_in[3];
    const float* Wk = (const float*)d_in[4];
    const float* bk = (const float*)d_in[5];
    const float* Wv = (const float*)d_in[6];
    const float* bv = (const float*)d_in[7];
    const float* W1 = (const float*)d_in[8];
    const float* b1 = (const float*)d_in[9];
    const float* W2 = (const float*)d_in[10];
    const float* b2 = (const float*)d_in[11];
    const float* ln1_g = (const float*)d_in[12];
    const float* ln1_b = (const float*)d_in[13];
    const float* ln2_g = (const float*)d_in[14];
    const float* ln2_b = (const float*)d_in[15];
    float* out = (float*)d_out;

    // workspace carve (floats)
    float* Q        = (float*)d_ws;                      // 576000
    float* K        = Q + 576000;
    float* V        = K + 576000;
    float* Vmean    = V + 576000;                        // 576
    float* measure  = Vmean + 576;                       // 16000
    float* attn_out = measure + 16000;                   // 576000
    float* h1       = attn_out + 576000;                 // 576000
    int*   qlist    = (int*)(h1 + 576000);               // 4000 ints
    int*   slot_map = qlist + 4000;                      // 16000 ints
    float* part     = (float*)(slot_map + 16000);        // 4,000,000
    float* f1       = part;                              // fallback only
    float* KT       = part + 4000000;                    // 576,000

    // transposed weights alias the part region when it's dead:
    float* WqT = part;                                   // dead before attn_part
    float* WkT = WqT + 82944;
    float* WvT = WkT + 82944;
    float* W1T = part;                                   // part dead after combine_all
    float* W2T = part + 165888;

    const size_t kt_end = 2916576ull + 4000000ull + 576000ull;  // ~30 MB
    const bool   big    = ws_size >= kt_end * sizeof(float);
    const int    nchunk = big ? 25 : 8;
    const int    chunk_len = L_ / nchunk;

    if (big) {
        qkv_transpose_kernel<<<243, 256, 0, stream>>>(Wq, Wk, Wv, WqT, WkT, WvT);
        qkvT2_kernel<<<500, 256, 0, stream>>>(x, WqT, WkT, WvT, bq, bk, bv, Q, K, V);
    } else {
        qkv_kernel<<<250, 320, 0, stream>>>(x, Wq, bq, Wk, bk, Wv, bv, Q, K, V);
    }
    vmean_kernel<<<BH_, 256, 0, stream>>>(V, Vmean);
    if (big) {
        ktranspose_kernel<<<BH_ * 64, 256, 0, stream>>>(K, KT);
        score_measure3_kernel<<<BH_ * 125, 256, 0, stream>>>(Q, KT, index_key, measure);
    } else {
        measure_kernel<<<4000, 256, 0, stream>>>(Q, K, index_key, measure);
    }
    topk_rank_kernel<<<BH_ * 4, 256, 0, stream>>>(measure, qlist, slot_map);
    attn_part_kernel<<<BH_ * nchunk, 256, 0, stream>>>(Q, K, V, qlist, part, nchunk, chunk_len);
    combine_all_kernel<<<(B_ * L_ * D_ + 255) / 256, 256, 0, stream>>>(
        part, slot_map, Vmean, attn_out, nchunk);
    ln1_kernel<<<B_ * L_, 64, 0, stream>>>(x, attn_out, ln1_g, ln1_b, h1);
    if (big) {
        ffn_transpose_kernel<<<324, 256, 0, stream>>>(W1, W2, W1T, W2T);
        ffn_fused2b_kernel<<<500, 288, 0, stream>>>(h1, W1T, b1, W2T, b2, ln2_g, ln2_b, out);
    } else {
        ffn1_kernel<<<250, 192, 0, stream>>>(h1, W1, b1, f1);
        ffn2_ln_kernel<<<250, 320, 0, stream>>>(f1, h1, W2, b2, ln2_g, ln2_b, out);
    }
}